// Round 14
// baseline (512.097 us; speedup 1.0000x reference)
//
#include <hip/hip_runtime.h>
#include <hip/hip_bf16.h>
#include <math.h>

#define L_   1024
#define DM_  2048
#define DI_  4096
#define DR_  128
#define DS_  16
#define DBC_ 160   // DR + 2*DS

typedef __attribute__((ext_vector_type(4))) float f32x4;
typedef __attribute__((ext_vector_type(8))) short s16x8;

__device__ inline unsigned short f2b(float f) {  // RNE f32->bf16
  unsigned int u = __float_as_uint(f);
  u += 0x7fffu + ((u >> 16) & 1u);
  return (unsigned short)(u >> 16);
}
__device__ inline float b2f(unsigned short u) {
  return __uint_as_float(((unsigned int)u) << 16);
}

__device__ inline void gload_lds16(const void* g, void* l) {
  __builtin_amdgcn_global_load_lds(
      (const __attribute__((address_space(1))) void*)g,
      (__attribute__((address_space(3))) void*)l, 16, 0, 0);
}

// ---- fused RMSNorm (blocks 0..1023) + weight f32->bf16 convert (rest) ------
// converts in_proj, out_proj, x_proj (dt_proj stays f32; consumed by ssm)
__launch_bounds__(256)
__global__ void rms_convert_kernel(const float* __restrict__ x, const float* __restrict__ w,
                                   unsigned short* __restrict__ xnb,
                                   const float* __restrict__ w_in, const float* __restrict__ w_out,
                                   const float* __restrict__ w_xp,
                                   unsigned short* __restrict__ wib, unsigned short* __restrict__ wob,
                                   unsigned short* __restrict__ xpwb) {
  if (blockIdx.x < L_) {
    int l = blockIdx.x;
    const float4* xr = (const float4*)(x + (size_t)l * DM_);
    const float4* wr = (const float4*)w;
    float4 v0 = xr[threadIdx.x];
    float4 v1 = xr[threadIdx.x + 256];
    float ss = v0.x*v0.x + v0.y*v0.y + v0.z*v0.z + v0.w*v0.w
             + v1.x*v1.x + v1.y*v1.y + v1.z*v1.z + v1.w*v1.w;
    for (int off = 32; off > 0; off >>= 1) ss += __shfl_down(ss, off, 64);
    __shared__ float sbuf[4];
    int lane = threadIdx.x & 63, wid = threadIdx.x >> 6;
    if (lane == 0) sbuf[wid] = ss;
    __syncthreads();
    float tot = sbuf[0] + sbuf[1] + sbuf[2] + sbuf[3];
    float scale = rsqrtf(tot / (float)DM_ + 1e-5f);
    float4 w0 = wr[threadIdx.x], w1 = wr[threadIdx.x + 256];
    float4 o0, o1;
    o0.x = v0.x * scale * w0.x; o0.y = v0.y * scale * w0.y;
    o0.z = v0.z * scale * w0.z; o0.w = v0.w * scale * w0.w;
    o1.x = v1.x * scale * w1.x; o1.y = v1.y * scale * w1.y;
    o1.z = v1.z * scale * w1.z; o1.w = v1.w * scale * w1.w;
    uint2 p0, p1;
    p0.x = (unsigned)f2b(o0.x) | ((unsigned)f2b(o0.y) << 16);
    p0.y = (unsigned)f2b(o0.z) | ((unsigned)f2b(o0.w) << 16);
    p1.x = (unsigned)f2b(o1.x) | ((unsigned)f2b(o1.y) << 16);
    p1.y = (unsigned)f2b(o1.z) | ((unsigned)f2b(o1.w) << 16);
    uint2* ob = (uint2*)(xnb + (size_t)l * DM_);
    ob[threadIdx.x] = p0;
    ob[threadIdx.x + 256] = p1;
    return;
  }
  const int N1 = 2 * DI_ * DM_ / 4;
  const int N2 = DM_ * DI_ / 4;
  const int N4 = DBC_ * DI_ / 4;
  int i = (blockIdx.x - L_) * 256 + threadIdx.x;
  const float* src; unsigned short* dst; int off;
  if (i < N1)                { src = w_in;  dst = wib;  off = i; }
  else if (i < N1 + N2)      { src = w_out; dst = wob;  off = i - N1; }
  else if (i < N1 + N2 + N4) { src = w_xp;  dst = xpwb; off = i - N1 - N2; }
  else return;
  float4 v = ((const float4*)src)[off];
  uint2 p;
  p.x = (unsigned)f2b(v.x) | ((unsigned)f2b(v.y) << 16);
  p.y = (unsigned)f2b(v.z) | ((unsigned)f2b(v.w) << 16);
  ((uint2*)dst)[off] = p;
}

// ---------------- bf16 MFMA GEMM: 128x128, 4 waves, 2-phase dbuf ------------
// EPI 3: plain -> bf16
template<int EPI>
__launch_bounds__(256)
__global__ void gemm_bf16_mfma(const unsigned short* __restrict__ A,
                               const unsigned short* __restrict__ W,
                               void* __restrict__ Cv_, int M, int N, int K,
                               const float* __restrict__ aux) {
  __shared__ unsigned short As[2][128 * 32];
  __shared__ unsigned short Ws[2][128 * 32];
  int nwg = gridDim.x * gridDim.y;
  int flat = blockIdx.y * gridDim.x + blockIdx.x;
  int q8 = nwg >> 3;
  int swz = (flat & 7) * q8 + (flat >> 3);
  int bxi = swz % gridDim.x, byi = swz / gridDim.x;
  int bm = byi * 128, bn = bxi * 128;
  int tid = threadIdx.x;
  int w = tid >> 6, lane = tid & 63;
  int wr = (w >> 1) * 64, wc = (w & 1) * 64;
  int ch0 = w * 64 + lane, ch1 = (4 + w) * 64 + lane;
  int row0 = ch0 >> 2, kc0 = ch0 & 3;
  int row1 = ch1 >> 2, kc1 = ch1 & 3;

  f32x4 acc[4][4];
#pragma unroll
  for (int m = 0; m < 4; m++)
#pragma unroll
    for (int n = 0; n < 4; n++) acc[m][n] = (f32x4){0.f, 0.f, 0.f, 0.f};

  int kb = lane >> 4, r = lane & 15;

#define STAGE_(buf, k0)                                                          \
  do {                                                                           \
    gload_lds16(A + (size_t)(bm + row0) * K + (k0) + kc0 * 8, &As[buf][ch0 * 8]);\
    gload_lds16(W + (size_t)(bn + row0) * K + (k0) + kc0 * 8, &Ws[buf][ch0 * 8]);\
    gload_lds16(A + (size_t)(bm + row1) * K + (k0) + kc1 * 8, &As[buf][ch1 * 8]);\
    gload_lds16(W + (size_t)(bn + row1) * K + (k0) + kc1 * 8, &Ws[buf][ch1 * 8]);\
  } while (0)

  STAGE_(0, 0);
  __syncthreads();
  int nt = K >> 5;
  for (int t = 0; t < nt; t++) {
    int cur = t & 1;
    if (t + 1 < nt) STAGE_(cur ^ 1, (t + 1) * 32);
    s16x8 a[4], b[4];
#pragma unroll
    for (int m = 0; m < 4; m++)
      a[m] = *(const s16x8*)(&As[cur][(wr + m * 16 + r) * 32 + kb * 8]);
#pragma unroll
    for (int n = 0; n < 4; n++)
      b[n] = *(const s16x8*)(&Ws[cur][(wc + n * 16 + r) * 32 + kb * 8]);
#pragma unroll
    for (int m = 0; m < 4; m++)
#pragma unroll
      for (int n = 0; n < 4; n++)
        acc[m][n] = __builtin_amdgcn_mfma_f32_16x16x32_bf16(a[m], b[n], acc[m][n], 0, 0, 0);
    __syncthreads();
  }
#undef STAGE_
  int q = lane >> 4;
#pragma unroll
  for (int m = 0; m < 4; m++) {
#pragma unroll
    for (int n = 0; n < 4; n++) {
#pragma unroll
      for (int j = 0; j < 4; j++) {
        int row = bm + wr + m * 16 + q * 4 + j;
        int col = bn + wc + n * 16 + r;
        float v = acc[m][n][j];
        if (EPI == 3) {
          ((unsigned short*)Cv_)[(size_t)row * N + col] = f2b(v);
        }
      }
    }
  }
}

// ------- bf16 MFMA GEMM, BM=64 x BN=128; residual aux (bf16) add, f32 out ---
__launch_bounds__(256)
__global__ void gemm_bf16_mfma_bm64(const unsigned short* __restrict__ A,
                                    const unsigned short* __restrict__ W,
                                    float* __restrict__ C, int M, int N, int K,
                                    const unsigned short* __restrict__ auxb) {
  __shared__ unsigned short As[2][64 * 32];
  __shared__ unsigned short Ws[2][128 * 32];
  int nwg = gridDim.x * gridDim.y;
  int flat = blockIdx.y * gridDim.x + blockIdx.x;
  int q8 = nwg >> 3;
  int swz = (flat & 7) * q8 + (flat >> 3);
  int bxi = swz % gridDim.x, byi = swz / gridDim.x;
  int bm = byi * 64, bn = bxi * 128;
  int tid = threadIdx.x;
  int w = tid >> 6, lane = tid & 63;
  int wr = (w >> 1) * 32, wc = (w & 1) * 64;
  int chA = w * 64 + lane;               // 0..255
  int rowA = chA >> 2, kcA = chA & 3;
  int ch0 = w * 64 + lane, ch1 = (4 + w) * 64 + lane;
  int row0 = ch0 >> 2, kc0 = ch0 & 3;
  int row1 = ch1 >> 2, kc1 = ch1 & 3;
  f32x4 acc[2][4];
#pragma unroll
  for (int m = 0; m < 2; m++)
#pragma unroll
    for (int n = 0; n < 4; n++) acc[m][n] = (f32x4){0.f, 0.f, 0.f, 0.f};

  int kb = lane >> 4, r = lane & 15;

#define STAGE_(buf, k0)                                                          \
  do {                                                                           \
    gload_lds16(A + (size_t)(bm + rowA) * K + (k0) + kcA * 8, &As[buf][chA * 8]);\
    gload_lds16(W + (size_t)(bn + row0) * K + (k0) + kc0 * 8, &Ws[buf][ch0 * 8]);\
    gload_lds16(W + (size_t)(bn + row1) * K + (k0) + kc1 * 8, &Ws[buf][ch1 * 8]);\
  } while (0)

  STAGE_(0, 0);
  __syncthreads();
  int nt = K >> 5;
  for (int t = 0; t < nt; t++) {
    int cur = t & 1;
    if (t + 1 < nt) STAGE_(cur ^ 1, (t + 1) * 32);
    s16x8 a[2], b[4];
#pragma unroll
    for (int m = 0; m < 2; m++)
      a[m] = *(const s16x8*)(&As[cur][(wr + m * 16 + r) * 32 + kb * 8]);
#pragma unroll
    for (int n = 0; n < 4; n++)
      b[n] = *(const s16x8*)(&Ws[cur][(wc + n * 16 + r) * 32 + kb * 8]);
#pragma unroll
    for (int m = 0; m < 2; m++)
#pragma unroll
      for (int n = 0; n < 4; n++)
        acc[m][n] = __builtin_amdgcn_mfma_f32_16x16x32_bf16(a[m], b[n], acc[m][n], 0, 0, 0);
    __syncthreads();
  }
#undef STAGE_
  int q = lane >> 4;
#pragma unroll
  for (int m = 0; m < 2; m++) {
#pragma unroll
    for (int n = 0; n < 4; n++) {
#pragma unroll
      for (int j = 0; j < 4; j++) {
        int row = bm + wr + m * 16 + q * 4 + j;
        int col = bn + wc + n * 16 + r;
        C[(size_t)row * N + col] = acc[m][n][j] + b2f(auxb[(size_t)row * N + col]);
      }
    }
  }
}

// ------- depthwise conv1d (K=3, pad 1) + SiLU: bf16 in/out, 8 elems/thread --
__launch_bounds__(256)
__global__ void conv_silu_kernel(const unsigned short* __restrict__ xzb, const float* __restrict__ cw,
                                 const float* __restrict__ cb, unsigned short* __restrict__ xcb) {
  int i8 = (blockIdx.x * 256 + threadIdx.x) * 8;   // over L*DI
  int l = i8 >> 12, d0 = i8 & (DI_ - 1);
  const unsigned short* base = xzb + (size_t)l * (2 * DI_) + d0;
  s16x8 vm = {}, vp = {};
  s16x8 v0 = *(const s16x8*)base;
  if (l > 0)      vm = *(const s16x8*)(base - 2 * DI_);
  if (l < L_ - 1) vp = *(const s16x8*)(base + 2 * DI_);
  float wv[24];
#pragma unroll
  for (int j = 0; j < 6; j++) *(float4*)&wv[j * 4] = *(const float4*)&cw[d0 * 3 + j * 4];
  float bv[8];
  *(float4*)&bv[0] = *(const float4*)&cb[d0];
  *(float4*)&bv[4] = *(const float4*)&cb[d0 + 4];
  unsigned short outv[8];
#pragma unroll
  for (int j = 0; j < 8; j++) {
    float acc = bv[j];
    acc = fmaf(wv[j * 3 + 0], b2f(((const unsigned short*)&vm)[j]), acc);
    acc = fmaf(wv[j * 3 + 1], b2f(((const unsigned short*)&v0)[j]), acc);
    acc = fmaf(wv[j * 3 + 2], b2f(((const unsigned short*)&vp)[j]), acc);
    float sig = 1.f / (1.f + __expf(-acc));
    outv[j] = f2b(acc * sig);
  }
  *(s16x8*)(xcb + i8) = *(s16x8*)outv;
}

// ---------------- xproj stage1, bf16 MFMA split-K, 2-phase dbuf -------------
__launch_bounds__(256)
__global__ void xproj_stage1_mfma(const unsigned short* __restrict__ xcb,
                                  const unsigned short* __restrict__ Wb,
                                  float* __restrict__ part) {
  __shared__ unsigned short As[2][64 * 32];
  __shared__ unsigned short Bs[2][160 * 32];
  int sp = blockIdx.x;
  int l0 = blockIdx.y * 64;
  int tid = threadIdx.x, w = tid >> 6, lane = tid & 63;
  int wr = (w >> 1) * 32, wc = (w & 1) * 80;
  int kb = lane >> 4, r = lane & 15;
  int chA = w * 64 + lane;
  int rowA = chA >> 2, kcA = chA & 3;
  f32x4 acc[2][5];
#pragma unroll
  for (int m = 0; m < 2; m++)
#pragma unroll
    for (int n = 0; n < 5; n++) acc[m][n] = (f32x4){0.f, 0.f, 0.f, 0.f};

#define STAGE_(buf, k0)                                                            \
  do {                                                                             \
    gload_lds16(xcb + (size_t)(l0 + rowA) * DI_ + (k0) + kcA * 8, &As[buf][chA * 8]);\
    _Pragma("unroll")                                                              \
    for (int i = 0; i < 3; i++) {                                                  \
      int g = i * 4 + w;                                                           \
      if (g < 10) {                                                                \
        int ch = g * 64 + lane;                                                    \
        int row = ch >> 2, kc = ch & 3;                                            \
        gload_lds16(Wb + (size_t)row * DI_ + (k0) + kc * 8, &Bs[buf][ch * 8]);     \
      }                                                                            \
    }                                                                              \
  } while (0)

  int kbase = sp * 256;
  STAGE_(0, kbase);
  __syncthreads();
  for (int kt = 0; kt < 8; kt++) {
    int cur = kt & 1;
    if (kt + 1 < 8) STAGE_(cur ^ 1, kbase + (kt + 1) * 32);
    s16x8 a[2], b[5];
#pragma unroll
    for (int m = 0; m < 2; m++)
      a[m] = *(const s16x8*)(&As[cur][(wr + m * 16 + r) * 32 + kb * 8]);
#pragma unroll
    for (int n = 0; n < 5; n++)
      b[n] = *(const s16x8*)(&Bs[cur][(wc + n * 16 + r) * 32 + kb * 8]);
#pragma unroll
    for (int m = 0; m < 2; m++)
#pragma unroll
      for (int n = 0; n < 5; n++)
        acc[m][n] = __builtin_amdgcn_mfma_f32_16x16x32_bf16(a[m], b[n], acc[m][n], 0, 0, 0);
    __syncthreads();
  }
#undef STAGE_
  int q = lane >> 4;
  float* pb = part + (size_t)sp * (L_ * DBC_) + (size_t)l0 * DBC_;
#pragma unroll
  for (int m = 0; m < 2; m++)
#pragma unroll
    for (int n = 0; n < 5; n++)
#pragma unroll
      for (int j = 0; j < 4; j++)
        pb[(size_t)(wr + m * 16 + q * 4 + j) * DBC_ + wc + n * 16 + r] = acc[m][n][j];
}

// ---------------- xproj stage2: dBC = sum over 16 splits --------------------
__launch_bounds__(256)
__global__ void xproj_stage2(const float* __restrict__ part, float* __restrict__ dBC) {
  int i = blockIdx.x * 256 + threadIdx.x;  // over L*DBC
  float s = 0.f;
#pragma unroll
  for (int sp = 0; sp < 16; sp++) s += part[(size_t)sp * (L_ * DBC_) + i];
  dBC[i] = s;
}

// -------- SSM elementwise + dt GEMV with REGISTER-resident weights ----------
// Thread (pair,q): d = d0+pair fixed across all 16 iterations (base increment
// 262144 === 0 mod DI). Its 32 dt weights dtw[d][q*32..q*32+32) load ONCE into
// VGPRs (compile-time indices; no LDS, no per-iter gather — fixes R11+R13).
// Per-iter GEMV cost: 8 float4 broadcast loads of dBC row + 32 reg-FMAs + 2 shfl.
__launch_bounds__(256)
__global__ void ssm_kernel5(const unsigned short* __restrict__ xzb, const unsigned short* __restrict__ xcb,
                            const float* __restrict__ dBC, const float* __restrict__ dtw,
                            const float* __restrict__ dt_b,
                            const float* __restrict__ h, const float* __restrict__ A_log,
                            const float* __restrict__ Dp, float* __restrict__ h_out,
                            unsigned short* __restrict__ yzb) {
  int pair = threadIdx.x >> 2;           // 0..63 -> d = d0 + pair
  int q = threadIdx.x & 3;               // s-quad AND dt k-quarter
  int d0 = (blockIdx.x & 63) << 6;
  int d = d0 + pair;
  // one-time: 32 dt weights into registers (8x float4, contiguous per lane)
  f32x4 wreg[8];
  const float* wsrc = dtw + (size_t)d * DR_ + q * 32;
#pragma unroll
  for (int j = 0; j < 8; j++) wreg[j] = *(const f32x4*)(wsrc + j * 4);
  float bias = dt_b[d];
  float Dv = Dp[d];
  float4 Al = *(const float4*)(A_log + (size_t)d * DS_ + q * 4);
  float4 An;
  An.x = -__expf(Al.x); An.y = -__expf(Al.y);
  An.z = -__expf(Al.z); An.w = -__expf(Al.w);
  for (int base = blockIdx.x * 64; base < L_ * DI_; base += gridDim.x * 64) {
    int idx = base + pair;
    int l = idx >> 12;
    // ---- delta = softplus(dBC[l,:128] . dtw[d,:] + dt_b[d]), f32 ----
    const float* dbc_l = dBC + (size_t)l * DBC_ + q * 32;
    float s = 0.f;
#pragma unroll
    for (int j = 0; j < 8; j++) {
      float4 a4 = *(const float4*)(dbc_l + j * 4);
      s = fmaf(a4.x, wreg[j][0], s);
      s = fmaf(a4.y, wreg[j][1], s);
      s = fmaf(a4.z, wreg[j][2], s);
      s = fmaf(a4.w, wreg[j][3], s);
    }
    s += __shfl_xor(s, 1, 64);
    s += __shfl_xor(s, 2, 64);
    float tt = s + bias;
    float dv = fmaxf(tt, 0.f) + log1pf(__expf(-fabsf(tt)));
    // ---- SSM state update ----
    float xv = b2f(xcb[idx]);
    float4 hv = *(const float4*)(h + (size_t)idx * DS_ + q * 4);
    float4 Bv = *(const float4*)(dBC + (size_t)l * DBC_ + DR_ + q * 4);
    float4 Cv = *(const float4*)(dBC + (size_t)l * DBC_ + DR_ + DS_ + q * 4);
    float4 hn;
    hn.x = __expf(dv * An.x) * hv.x + dv * Bv.x * xv;
    hn.y = __expf(dv * An.y) * hv.y + dv * Bv.y * xv;
    hn.z = __expf(dv * An.z) * hv.z + dv * Bv.z * xv;
    hn.w = __expf(dv * An.w) * hv.w + dv * Bv.w * xv;
    *(float4*)(h_out + (size_t)idx * DS_ + q * 4) = hn;
    float y = hn.x * Cv.x + hn.y * Cv.y + hn.z * Cv.z + hn.w * Cv.w;
    y += __shfl_xor(y, 1, 64);
    y += __shfl_xor(y, 2, 64);
    if (q == 0) {
      y = fmaf(Dv, xv, y);
      float zv = b2f(xzb[(size_t)l * (2 * DI_) + DI_ + d]);
      float sig = 1.f / (1.f + __expf(-zv));
      yzb[idx] = f2b(y * zv * sig);
    }
  }
}

extern "C" void kernel_launch(void* const* d_in, const int* in_sizes, int n_in,
                              void* d_out, int out_size, void* d_ws, size_t ws_size,
                              hipStream_t stream) {
  const float* x         = (const float*)d_in[0];
  const float* h         = (const float*)d_in[1];
  const float* norm_w    = (const float*)d_in[2];
  const float* in_proj_w = (const float*)d_in[3];
  const float* conv_w    = (const float*)d_in[4];
  const float* conv_b    = (const float*)d_in[5];
  const float* x_proj_w  = (const float*)d_in[6];
  const float* dt_proj_w = (const float*)d_in[7];
  const float* dt_proj_b = (const float*)d_in[8];
  const float* A_log     = (const float*)d_in[9];
  const float* Dvec      = (const float*)d_in[10];
  const float* out_projw = (const float*)d_in[11];

  float* out   = (float*)d_out;
  float* h_out = out + (size_t)L_ * DM_;

  float* ws    = (float*)d_ws;
  float* dBC   = ws;                               // L*DBC     =   163,840 f
  float* part  = dBC   + (size_t)L_ * DBC_;        // 16*L*DBC  = 2,621,440 f
  unsigned short* xnb   = (unsigned short*)(part + (size_t)16 * L_ * DBC_);
  unsigned short* wib   = xnb   + (size_t)L_ * DM_;       // 2*DI*DM = 16,777,216
  unsigned short* wob   = wib   + (size_t)2 * DI_ * DM_;  // DM*DI   =  8,388,608
  unsigned short* yzb   = wob   + (size_t)DM_ * DI_;      // L*DI    =  4,194,304
  unsigned short* xpwb  = yzb   + (size_t)L_ * DI_;       // DBC*DI  =   655,360
  unsigned short* xcb   = xpwb  + (size_t)DBC_ * DI_;     // L*DI    =  4,194,304
  unsigned short* xzb   = xcb   + (size_t)L_ * DI_;       // L*2*DI  =  8,388,608

  // 1. fused RMSNorm + weight conversions (in_proj, out_proj, x_proj)
  const int CONV_BLKS = (2 * DI_ * DM_ + DM_ * DI_ + DBC_ * DI_) / 4 / 256;
  rms_convert_kernel<<<L_ + CONV_BLKS, 256, 0, stream>>>(
      x, norm_w, xnb, in_proj_w, out_projw, x_proj_w, wib, wob, xpwb);
  // 2. xz = xn @ in_proj_w.T  [1024 x 8192], K=2048 -> bf16 (128x128, 2-phase)
  gemm_bf16_mfma<3><<<dim3(2 * DI_ / 128, L_ / 128), 256, 0, stream>>>(
      xnb, wib, xzb, L_, 2 * DI_, DM_, nullptr);
  // 3. depthwise conv + silu -> xcb (bf16), 8 elems/thread
  conv_silu_kernel<<<L_ * DI_ / 8 / 256, 256, 0, stream>>>(xzb, conv_w, conv_b, xcb);
  // 4. dBC = xc @ x_proj_w.T  [1024 x 160], K=4096 (bf16 MFMA split-K)
  xproj_stage1_mfma<<<dim3(16, 16), 256, 0, stream>>>(xcb, xpwb, part);
  xproj_stage2<<<L_ * DBC_ / 256, 256, 0, stream>>>(part, dBC);
  // 5. SSM + inline dt GEMV (register-resident weights): h_new + yz (bf16)
  ssm_kernel5<<<4096, 256, 0, stream>>>(
      xzb, xcb, dBC, dt_proj_w, dt_proj_b, h, A_log, Dvec, h_out, yzb);
  // 6. out = yz @ out_proj_w.T + xn(bf16)  [1024 x 2048], K=4096 (BM=64)
  gemm_bf16_mfma_bm64<<<dim3(DM_ / 128, L_ / 64), 256, 0, stream>>>(
      yzb, wob, out, L_, DM_, DI_, xnb);
}

// Round 15
// 314.606 us; speedup vs baseline: 1.6277x; 1.6277x over previous
//
#include <hip/hip_runtime.h>
#include <hip/hip_bf16.h>
#include <math.h>

#define L_   1024
#define DM_  2048
#define DI_  4096
#define DR_  128
#define DS_  16
#define DBC_ 160   // DR + 2*DS

typedef __attribute__((ext_vector_type(4))) float f32x4;
typedef __attribute__((ext_vector_type(8))) short s16x8;

__device__ inline unsigned short f2b(float f) {  // RNE f32->bf16
  unsigned int u = __float_as_uint(f);
  u += 0x7fffu + ((u >> 16) & 1u);
  return (unsigned short)(u >> 16);
}
__device__ inline float b2f(unsigned short u) {
  return __uint_as_float(((unsigned int)u) << 16);
}

__device__ inline void gload_lds16(const void* g, void* l) {
  __builtin_amdgcn_global_load_lds(
      (const __attribute__((address_space(1))) void*)g,
      (__attribute__((address_space(3))) void*)l, 16, 0, 0);
}

// ---- fused RMSNorm (blocks 0..1023) + weight f32->bf16 convert (rest) ------
__launch_bounds__(256)
__global__ void rms_convert_kernel(const float* __restrict__ x, const float* __restrict__ w,
                                   unsigned short* __restrict__ xnb,
                                   const float* __restrict__ w_in, const float* __restrict__ w_out,
                                   const float* __restrict__ w_dt, const float* __restrict__ w_xp,
                                   unsigned short* __restrict__ wib, unsigned short* __restrict__ wob,
                                   unsigned short* __restrict__ dtwb, unsigned short* __restrict__ xpwb) {
  if (blockIdx.x < L_) {
    int l = blockIdx.x;
    const float4* xr = (const float4*)(x + (size_t)l * DM_);
    const float4* wr = (const float4*)w;
    float4 v0 = xr[threadIdx.x];
    float4 v1 = xr[threadIdx.x + 256];
    float ss = v0.x*v0.x + v0.y*v0.y + v0.z*v0.z + v0.w*v0.w
             + v1.x*v1.x + v1.y*v1.y + v1.z*v1.z + v1.w*v1.w;
    for (int off = 32; off > 0; off >>= 1) ss += __shfl_down(ss, off, 64);
    __shared__ float sbuf[4];
    int lane = threadIdx.x & 63, wid = threadIdx.x >> 6;
    if (lane == 0) sbuf[wid] = ss;
    __syncthreads();
    float tot = sbuf[0] + sbuf[1] + sbuf[2] + sbuf[3];
    float scale = rsqrtf(tot / (float)DM_ + 1e-5f);
    float4 w0 = wr[threadIdx.x], w1 = wr[threadIdx.x + 256];
    float4 o0, o1;
    o0.x = v0.x * scale * w0.x; o0.y = v0.y * scale * w0.y;
    o0.z = v0.z * scale * w0.z; o0.w = v0.w * scale * w0.w;
    o1.x = v1.x * scale * w1.x; o1.y = v1.y * scale * w1.y;
    o1.z = v1.z * scale * w1.z; o1.w = v1.w * scale * w1.w;
    uint2 p0, p1;
    p0.x = (unsigned)f2b(o0.x) | ((unsigned)f2b(o0.y) << 16);
    p0.y = (unsigned)f2b(o0.z) | ((unsigned)f2b(o0.w) << 16);
    p1.x = (unsigned)f2b(o1.x) | ((unsigned)f2b(o1.y) << 16);
    p1.y = (unsigned)f2b(o1.z) | ((unsigned)f2b(o1.w) << 16);
    uint2* ob = (uint2*)(xnb + (size_t)l * DM_);
    ob[threadIdx.x] = p0;
    ob[threadIdx.x + 256] = p1;
    return;
  }
  const int N1 = 2 * DI_ * DM_ / 4;
  const int N2 = DM_ * DI_ / 4;
  const int N3 = DI_ * DR_ / 4;
  const int N4 = DBC_ * DI_ / 4;
  int i = (blockIdx.x - L_) * 256 + threadIdx.x;
  const float* src; unsigned short* dst; int off;
  if (i < N1)                { src = w_in;  dst = wib;  off = i; }
  else if (i < N1 + N2)      { src = w_out; dst = wob;  off = i - N1; }
  else if (i < N1 + N2 + N3) { src = w_dt;  dst = dtwb; off = i - N1 - N2; }
  else if (i < N1 + N2 + N3 + N4) { src = w_xp; dst = xpwb; off = i - N1 - N2 - N3; }
  else return;
  float4 v = ((const float4*)src)[off];
  uint2 p;
  p.x = (unsigned)f2b(v.x) | ((unsigned)f2b(v.y) << 16);
  p.y = (unsigned)f2b(v.z) | ((unsigned)f2b(v.w) << 16);
  ((uint2*)dst)[off] = p;
}

// ---------------- bf16 MFMA GEMM: 128x128, 4 waves, 2-phase dbuf ------------
// EPI 1: softplus(acc+aux[n]) -> bf16; EPI 3: plain -> bf16
template<int EPI>
__launch_bounds__(256)
__global__ void gemm_bf16_mfma(const unsigned short* __restrict__ A,
                               const unsigned short* __restrict__ W,
                               void* __restrict__ Cv_, int M, int N, int K,
                               const float* __restrict__ aux) {
  __shared__ unsigned short As[2][128 * 32];
  __shared__ unsigned short Ws[2][128 * 32];
  int nwg = gridDim.x * gridDim.y;
  int flat = blockIdx.y * gridDim.x + blockIdx.x;
  int q8 = nwg >> 3;
  int swz = (flat & 7) * q8 + (flat >> 3);
  int bxi = swz % gridDim.x, byi = swz / gridDim.x;
  int bm = byi * 128, bn = bxi * 128;
  int tid = threadIdx.x;
  int w = tid >> 6, lane = tid & 63;
  int wr = (w >> 1) * 64, wc = (w & 1) * 64;
  int ch0 = w * 64 + lane, ch1 = (4 + w) * 64 + lane;
  int row0 = ch0 >> 2, kc0 = ch0 & 3;
  int row1 = ch1 >> 2, kc1 = ch1 & 3;

  f32x4 acc[4][4];
#pragma unroll
  for (int m = 0; m < 4; m++)
#pragma unroll
    for (int n = 0; n < 4; n++) acc[m][n] = (f32x4){0.f, 0.f, 0.f, 0.f};

  int kb = lane >> 4, r = lane & 15;

#define STAGE_(buf, k0)                                                          \
  do {                                                                           \
    gload_lds16(A + (size_t)(bm + row0) * K + (k0) + kc0 * 8, &As[buf][ch0 * 8]);\
    gload_lds16(W + (size_t)(bn + row0) * K + (k0) + kc0 * 8, &Ws[buf][ch0 * 8]);\
    gload_lds16(A + (size_t)(bm + row1) * K + (k0) + kc1 * 8, &As[buf][ch1 * 8]);\
    gload_lds16(W + (size_t)(bn + row1) * K + (k0) + kc1 * 8, &Ws[buf][ch1 * 8]);\
  } while (0)

  STAGE_(0, 0);
  __syncthreads();
  int nt = K >> 5;
  for (int t = 0; t < nt; t++) {
    int cur = t & 1;
    if (t + 1 < nt) STAGE_(cur ^ 1, (t + 1) * 32);
    s16x8 a[4], b[4];
#pragma unroll
    for (int m = 0; m < 4; m++)
      a[m] = *(const s16x8*)(&As[cur][(wr + m * 16 + r) * 32 + kb * 8]);
#pragma unroll
    for (int n = 0; n < 4; n++)
      b[n] = *(const s16x8*)(&Ws[cur][(wc + n * 16 + r) * 32 + kb * 8]);
#pragma unroll
    for (int m = 0; m < 4; m++)
#pragma unroll
      for (int n = 0; n < 4; n++)
        acc[m][n] = __builtin_amdgcn_mfma_f32_16x16x32_bf16(a[m], b[n], acc[m][n], 0, 0, 0);
    __syncthreads();
  }
#undef STAGE_
  int q = lane >> 4;
#pragma unroll
  for (int m = 0; m < 4; m++) {
#pragma unroll
    for (int n = 0; n < 4; n++) {
#pragma unroll
      for (int j = 0; j < 4; j++) {
        int row = bm + wr + m * 16 + q * 4 + j;
        int col = bn + wc + n * 16 + r;
        float v = acc[m][n][j];
        if (EPI == 1) {
          v += aux[col];
          v = fmaxf(v, 0.f) + log1pf(__expf(-fabsf(v)));
          ((unsigned short*)Cv_)[(size_t)row * N + col] = f2b(v);
        }
        if (EPI == 3) {
          ((unsigned short*)Cv_)[(size_t)row * N + col] = f2b(v);
        }
      }
    }
  }
}

// ------- bf16 MFMA GEMM, BM=64 x BN=128; residual aux (bf16) add, f32 out ---
__launch_bounds__(256)
__global__ void gemm_bf16_mfma_bm64(const unsigned short* __restrict__ A,
                                    const unsigned short* __restrict__ W,
                                    float* __restrict__ C, int M, int N, int K,
                                    const unsigned short* __restrict__ auxb) {
  __shared__ unsigned short As[2][64 * 32];
  __shared__ unsigned short Ws[2][128 * 32];
  int nwg = gridDim.x * gridDim.y;
  int flat = blockIdx.y * gridDim.x + blockIdx.x;
  int q8 = nwg >> 3;
  int swz = (flat & 7) * q8 + (flat >> 3);
  int bxi = swz % gridDim.x, byi = swz / gridDim.x;
  int bm = byi * 64, bn = bxi * 128;
  int tid = threadIdx.x;
  int w = tid >> 6, lane = tid & 63;
  int wr = (w >> 1) * 32, wc = (w & 1) * 64;
  int chA = w * 64 + lane;               // 0..255
  int rowA = chA >> 2, kcA = chA & 3;
  int ch0 = w * 64 + lane, ch1 = (4 + w) * 64 + lane;
  int row0 = ch0 >> 2, kc0 = ch0 & 3;
  int row1 = ch1 >> 2, kc1 = ch1 & 3;
  f32x4 acc[2][4];
#pragma unroll
  for (int m = 0; m < 2; m++)
#pragma unroll
    for (int n = 0; n < 4; n++) acc[m][n] = (f32x4){0.f, 0.f, 0.f, 0.f};

  int kb = lane >> 4, r = lane & 15;

#define STAGE_(buf, k0)                                                          \
  do {                                                                           \
    gload_lds16(A + (size_t)(bm + rowA) * K + (k0) + kcA * 8, &As[buf][chA * 8]);\
    gload_lds16(W + (size_t)(bn + row0) * K + (k0) + kc0 * 8, &Ws[buf][ch0 * 8]);\
    gload_lds16(W + (size_t)(bn + row1) * K + (k0) + kc1 * 8, &Ws[buf][ch1 * 8]);\
  } while (0)

  STAGE_(0, 0);
  __syncthreads();
  int nt = K >> 5;
  for (int t = 0; t < nt; t++) {
    int cur = t & 1;
    if (t + 1 < nt) STAGE_(cur ^ 1, (t + 1) * 32);
    s16x8 a[2], b[4];
#pragma unroll
    for (int m = 0; m < 2; m++)
      a[m] = *(const s16x8*)(&As[cur][(wr + m * 16 + r) * 32 + kb * 8]);
#pragma unroll
    for (int n = 0; n < 4; n++)
      b[n] = *(const s16x8*)(&Ws[cur][(wc + n * 16 + r) * 32 + kb * 8]);
#pragma unroll
    for (int m = 0; m < 2; m++)
#pragma unroll
      for (int n = 0; n < 4; n++)
        acc[m][n] = __builtin_amdgcn_mfma_f32_16x16x32_bf16(a[m], b[n], acc[m][n], 0, 0, 0);
    __syncthreads();
  }
#undef STAGE_
  int q = lane >> 4;
#pragma unroll
  for (int m = 0; m < 2; m++) {
#pragma unroll
    for (int n = 0; n < 4; n++) {
#pragma unroll
      for (int j = 0; j < 4; j++) {
        int row = bm + wr + m * 16 + q * 4 + j;
        int col = bn + wc + n * 16 + r;
        C[(size_t)row * N + col] = acc[m][n][j] + b2f(auxb[(size_t)row * N + col]);
      }
    }
  }
}

// ------- depthwise conv1d (K=3, pad 1) + SiLU: bf16 in/out, 8 elems/thread --
__launch_bounds__(256)
__global__ void conv_silu_kernel(const unsigned short* __restrict__ xzb, const float* __restrict__ cw,
                                 const float* __restrict__ cb, unsigned short* __restrict__ xcb) {
  int i8 = (blockIdx.x * 256 + threadIdx.x) * 8;   // over L*DI
  int l = i8 >> 12, d0 = i8 & (DI_ - 1);
  const unsigned short* base = xzb + (size_t)l * (2 * DI_) + d0;
  s16x8 vm = {}, vp = {};
  s16x8 v0 = *(const s16x8*)base;
  if (l > 0)      vm = *(const s16x8*)(base - 2 * DI_);
  if (l < L_ - 1) vp = *(const s16x8*)(base + 2 * DI_);
  float wv[24];
#pragma unroll
  for (int j = 0; j < 6; j++) *(float4*)&wv[j * 4] = *(const float4*)&cw[d0 * 3 + j * 4];
  float bv[8];
  *(float4*)&bv[0] = *(const float4*)&cb[d0];
  *(float4*)&bv[4] = *(const float4*)&cb[d0 + 4];
  unsigned short outv[8];
#pragma unroll
  for (int j = 0; j < 8; j++) {
    float acc = bv[j];
    acc = fmaf(wv[j * 3 + 0], b2f(((const unsigned short*)&vm)[j]), acc);
    acc = fmaf(wv[j * 3 + 1], b2f(((const unsigned short*)&v0)[j]), acc);
    acc = fmaf(wv[j * 3 + 2], b2f(((const unsigned short*)&vp)[j]), acc);
    float sig = 1.f / (1.f + __expf(-acc));
    outv[j] = f2b(acc * sig);
  }
  *(s16x8*)(xcb + i8) = *(s16x8*)outv;
}

// ---------------- xproj stage1, bf16 MFMA split-K, 2-phase dbuf -------------
__launch_bounds__(256)
__global__ void xproj_stage1_mfma(const unsigned short* __restrict__ xcb,
                                  const unsigned short* __restrict__ Wb,
                                  float* __restrict__ part) {
  __shared__ unsigned short As[2][64 * 32];
  __shared__ unsigned short Bs[2][160 * 32];
  int sp = blockIdx.x;
  int l0 = blockIdx.y * 64;
  int tid = threadIdx.x, w = tid >> 6, lane = tid & 63;
  int wr = (w >> 1) * 32, wc = (w & 1) * 80;
  int kb = lane >> 4, r = lane & 15;
  int chA = w * 64 + lane;
  int rowA = chA >> 2, kcA = chA & 3;
  f32x4 acc[2][5];
#pragma unroll
  for (int m = 0; m < 2; m++)
#pragma unroll
    for (int n = 0; n < 5; n++) acc[m][n] = (f32x4){0.f, 0.f, 0.f, 0.f};

#define STAGE_(buf, k0)                                                            \
  do {                                                                             \
    gload_lds16(xcb + (size_t)(l0 + rowA) * DI_ + (k0) + kcA * 8, &As[buf][chA * 8]);\
    _Pragma("unroll")                                                              \
    for (int i = 0; i < 3; i++) {                                                  \
      int g = i * 4 + w;                                                           \
      if (g < 10) {                                                                \
        int ch = g * 64 + lane;                                                    \
        int row = ch >> 2, kc = ch & 3;                                            \
        gload_lds16(Wb + (size_t)row * DI_ + (k0) + kc * 8, &Bs[buf][ch * 8]);     \
      }                                                                            \
    }                                                                              \
  } while (0)

  int kbase = sp * 256;
  STAGE_(0, kbase);
  __syncthreads();
  for (int kt = 0; kt < 8; kt++) {
    int cur = kt & 1;
    if (kt + 1 < 8) STAGE_(cur ^ 1, kbase + (kt + 1) * 32);
    s16x8 a[2], b[5];
#pragma unroll
    for (int m = 0; m < 2; m++)
      a[m] = *(const s16x8*)(&As[cur][(wr + m * 16 + r) * 32 + kb * 8]);
#pragma unroll
    for (int n = 0; n < 5; n++)
      b[n] = *(const s16x8*)(&Bs[cur][(wc + n * 16 + r) * 32 + kb * 8]);
#pragma unroll
    for (int m = 0; m < 2; m++)
#pragma unroll
      for (int n = 0; n < 5; n++)
        acc[m][n] = __builtin_amdgcn_mfma_f32_16x16x32_bf16(a[m], b[n], acc[m][n], 0, 0, 0);
    __syncthreads();
  }
#undef STAGE_
  int q = lane >> 4;
  float* pb = part + (size_t)sp * (L_ * DBC_) + (size_t)l0 * DBC_;
#pragma unroll
  for (int m = 0; m < 2; m++)
#pragma unroll
    for (int n = 0; n < 5; n++)
#pragma unroll
      for (int j = 0; j < 4; j++)
        pb[(size_t)(wr + m * 16 + q * 4 + j) * DBC_ + wc + n * 16 + r] = acc[m][n][j];
}

// ---------------- xproj stage2: dBC = sum splits; also bf16 dt rows ---------
__launch_bounds__(256)
__global__ void xproj_stage2(const float* __restrict__ part, float* __restrict__ dBC,
                             unsigned short* __restrict__ dtb) {
  int i = blockIdx.x * 256 + threadIdx.x;  // over L*DBC
  float s = 0.f;
#pragma unroll
  for (int sp = 0; sp < 16; sp++) s += part[(size_t)sp * (L_ * DBC_) + i];
  dBC[i] = s;
  int l = i / DBC_, col = i - l * DBC_;
  if (col < DR_) dtb[(size_t)l * DR_ + col] = f2b(s);
}

// ---------------- SSM elementwise, coalesced: 4 lanes per (l,d) -------------
__launch_bounds__(256)
__global__ void ssm_kernel2(const unsigned short* __restrict__ xzb, const unsigned short* __restrict__ xcb,
                            const float* __restrict__ dBC, const unsigned short* __restrict__ deltab,
                            const float* __restrict__ h, const float* __restrict__ A_log,
                            const float* __restrict__ Dp, float* __restrict__ h_out,
                            unsigned short* __restrict__ yzb) {
  int pair = threadIdx.x >> 2;           // 0..63 within block
  int q = threadIdx.x & 3;               // s-quad
  for (int base = blockIdx.x * 64; base < L_ * DI_; base += gridDim.x * 64) {
    int idx = base + pair;
    int l = idx >> 12, d = idx & (DI_ - 1);
    float dv = b2f(deltab[idx]);
    float xv = b2f(xcb[idx]);
    float4 hv = *(const float4*)(h + (size_t)idx * DS_ + q * 4);
    float4 Al = *(const float4*)(A_log + (size_t)d * DS_ + q * 4);
    float4 Bv = *(const float4*)(dBC + (size_t)l * DBC_ + DR_ + q * 4);
    float4 Cv = *(const float4*)(dBC + (size_t)l * DBC_ + DR_ + DS_ + q * 4);
    float4 hn;
    hn.x = __expf(dv * -__expf(Al.x)) * hv.x + dv * Bv.x * xv;
    hn.y = __expf(dv * -__expf(Al.y)) * hv.y + dv * Bv.y * xv;
    hn.z = __expf(dv * -__expf(Al.z)) * hv.z + dv * Bv.z * xv;
    hn.w = __expf(dv * -__expf(Al.w)) * hv.w + dv * Bv.w * xv;
    *(float4*)(h_out + (size_t)idx * DS_ + q * 4) = hn;
    float y = hn.x * Cv.x + hn.y * Cv.y + hn.z * Cv.z + hn.w * Cv.w;
    y += __shfl_xor(y, 1, 64);
    y += __shfl_xor(y, 2, 64);
    if (q == 0) {
      y = fmaf(Dp[d], xv, y);
      float zv = b2f(xzb[(size_t)l * (2 * DI_) + DI_ + d]);
      float sig = 1.f / (1.f + __expf(-zv));
      yzb[idx] = f2b(y * zv * sig);
    }
  }
}

extern "C" void kernel_launch(void* const* d_in, const int* in_sizes, int n_in,
                              void* d_out, int out_size, void* d_ws, size_t ws_size,
                              hipStream_t stream) {
  const float* x         = (const float*)d_in[0];
  const float* h         = (const float*)d_in[1];
  const float* norm_w    = (const float*)d_in[2];
  const float* in_proj_w = (const float*)d_in[3];
  const float* conv_w    = (const float*)d_in[4];
  const float* conv_b    = (const float*)d_in[5];
  const float* x_proj_w  = (const float*)d_in[6];
  const float* dt_proj_w = (const float*)d_in[7];
  const float* dt_proj_b = (const float*)d_in[8];
  const float* A_log     = (const float*)d_in[9];
  const float* Dvec      = (const float*)d_in[10];
  const float* out_projw = (const float*)d_in[11];

  float* out   = (float*)d_out;
  float* h_out = out + (size_t)L_ * DM_;

  float* ws    = (float*)d_ws;
  float* dBC   = ws;                               // L*DBC     =   163,840 f
  float* part  = dBC   + (size_t)L_ * DBC_;        // 16*L*DBC  = 2,621,440 f
  unsigned short* xnb   = (unsigned short*)(part + (size_t)16 * L_ * DBC_);
  unsigned short* wib   = xnb   + (size_t)L_ * DM_;       // 2*DI*DM = 16,777,216
  unsigned short* wob   = wib   + (size_t)2 * DI_ * DM_;  // DM*DI   =  8,388,608
  unsigned short* yzb   = wob   + (size_t)DM_ * DI_;      // L*DI    =  4,194,304
  unsigned short* dtb   = yzb   + (size_t)L_ * DI_;       // L*DR    =   131,072
  unsigned short* dtwb  = dtb   + (size_t)L_ * DR_;       // DI*DR   =   524,288
  unsigned short* xpwb  = dtwb  + (size_t)DI_ * DR_;      // DBC*DI  =   655,360
  unsigned short* xcb   = xpwb  + (size_t)DBC_ * DI_;     // L*DI    =  4,194,304
  unsigned short* xzb   = xcb   + (size_t)L_ * DI_;       // L*2*DI  =  8,388,608
  unsigned short* deltab= xzb   + (size_t)L_ * 2 * DI_;   // L*DI    =  4,194,304

  // 1. fused RMSNorm + weight conversions
  const int CONV_BLKS = (2 * DI_ * DM_ + DM_ * DI_ + DI_ * DR_ + DBC_ * DI_) / 4 / 256;
  rms_convert_kernel<<<L_ + CONV_BLKS, 256, 0, stream>>>(
      x, norm_w, xnb, in_proj_w, out_projw, dt_proj_w, x_proj_w, wib, wob, dtwb, xpwb);
  // 2. xz = xn @ in_proj_w.T  [1024 x 8192], K=2048 -> bf16 (128x128, 2-phase)
  gemm_bf16_mfma<3><<<dim3(2 * DI_ / 128, L_ / 128), 256, 0, stream>>>(
      xnb, wib, xzb, L_, 2 * DI_, DM_, nullptr);
  // 3. depthwise conv + silu -> xcb (bf16), 8 elems/thread
  conv_silu_kernel<<<L_ * DI_ / 8 / 256, 256, 0, stream>>>(xzb, conv_w, conv_b, xcb);
  // 4. dBC = xc @ x_proj_w.T  [1024 x 160], K=4096 (bf16 MFMA split-K)
  xproj_stage1_mfma<<<dim3(16, 16), 256, 0, stream>>>(xcb, xpwb, part);
  xproj_stage2<<<L_ * DBC_ / 256, 256, 0, stream>>>(part, dBC, dtb);
  // 5. delta = softplus(dtb @ dt_proj_w.T + dt_proj_b) -> bf16, K=128
  gemm_bf16_mfma<1><<<dim3(DI_ / 128, L_ / 128), 256, 0, stream>>>(
      dtb, dtwb, deltab, L_, DI_, DR_, dt_proj_b);
  // 6. SSM elementwise: h_new (to output) + yz (bf16)
  ssm_kernel2<<<4096, 256, 0, stream>>>(
      xzb, xcb, dBC, deltab, h, A_log, Dvec, h_out, yzb);
  // 7. out = yz @ out_proj_w.T + xn(bf16)  [1024 x 2048], K=4096 (BM=64)
  gemm_bf16_mfma_bm64<<<dim3(DM_ / 128, L_ / 64), 256, 0, stream>>>(
      yzb, wob, out, L_, DM_, DI_, xnb);
}